// Round 12
// baseline (265.500 us; speedup 1.0000x reference)
//
#include <hip/hip_runtime.h>
#include <hip/hip_fp16.h>

typedef __attribute__((ext_vector_type(4)))  int   i32x4;
typedef __attribute__((ext_vector_type(16))) int   i32x16;

#define ALPHA 32
#define BM 256
#define BN 256
#define BK 64

// Tiled int8 workspace layout (matches LDS staging & fragment reads):
//   addr(row,k) = (row>>5)*(32*K) + (k>>4)*512 + (row&31)*16 + (k&15)

// ---------------- kernel A: top-32 of |act_max| + keep-bitmask ----------------
__global__ __launch_bounds__(256) void topk_kernel(const float* __restrict__ act_max,
                                                   int* __restrict__ idx_out,
                                                   unsigned* __restrict__ tbits,
                                                   int K) {
  __shared__ float rv[4];
  __shared__ int   ri[4];
  __shared__ unsigned bits[128];
  __shared__ int bsel;
  const int t = threadIdx.x, w = t >> 6;
  float vloc[16];
#pragma unroll
  for (int jj = 0; jj < 16; ++jj) vloc[jj] = fabsf(act_max[jj * 256 + t]);
  for (int i = t; i < 128; i += 256) bits[i] = 0xFFFFFFFFu;
  __syncthreads();
  for (int sel = 0; sel < ALPHA; ++sel) {
    float bv = vloc[0]; int bi = t;          // ascending scan keeps lowest index on ties
#pragma unroll
    for (int jj = 1; jj < 16; ++jj)
      if (vloc[jj] > bv) { bv = vloc[jj]; bi = jj * 256 + t; }
    for (int m = 1; m < 64; m <<= 1) {
      float ov = __shfl_xor(bv, m);
      int   oi = __shfl_xor(bi, m);
      if (ov > bv || (ov == bv && oi < bi)) { bv = ov; bi = oi; }
    }
    if ((t & 63) == 0) { rv[w] = bv; ri[w] = bi; }
    __syncthreads();
    if (t == 0) {
      for (int u = 1; u < 4; ++u)
        if (rv[u] > bv || (rv[u] == bv && ri[u] < bi)) { bv = rv[u]; bi = ri[u]; }
      idx_out[sel] = bi;
      bits[bi >> 5] &= ~(1u << (bi & 31));
      bsel = bi;
    }
    __syncthreads();
    const int bs = bsel;
#pragma unroll
    for (int jj = 0; jj < 16; ++jj)
      if (jj * 256 + t == bs) vloc[jj] = -2.f;
    __syncthreads();
  }
  for (int i = t; i < 128; i += 256) tbits[i] = bits[i];
}

// ------------- kernel B: 12-rows-per-block quantization + gather -------------
__global__ __launch_bounds__(256) void quant12_kernel(
    const float* __restrict__ srcW, const float* __restrict__ srcX,
    const unsigned* __restrict__ tbits, const int* __restrict__ idxg,
    signed char* __restrict__ wq, signed char* __restrict__ xq,
    _Float16* __restrict__ wmax, _Float16* __restrict__ xmax,
    float* __restrict__ wuf, float* __restrict__ xuf,
    int K, int N, int M) {
  const int t = threadIdx.x, lane = t & 63, w = t >> 6;
  const int r0 = blockIdx.x * 12;
  __shared__ unsigned bits[128];
  __shared__ signed char qt[4 * 4096];   // 16 KB bounce (4 rows/phase)
  for (int i = t; i < 128; i += 256) bits[i] = tbits[i];
  __syncthreads();
  const int shft = (lane & 7) * 4;
#pragma unroll
  for (int g = 0; g < 3; ++g) {
    const int r = r0 + g * 4 + w;                       // this wave's global row
    const bool isW = r < N;                             // wave-uniform
    const float* srow = isW ? (srcW + (size_t)r * K) : (srcX + (size_t)(r - N) * K);
    const float4* srow4 = (const float4*)srow;
    float4 v[16];
    float am = 0.f;
#pragma unroll
    for (int j = 0; j < 16; ++j) {       // wave reads 1KB contiguous per instr
      float4 x = srow4[j * 64 + lane];
      unsigned b4 = bits[j * 8 + (lane >> 3)] >> shft;
      if (!(b4 & 1u)) x.x = 0.f;
      if (!(b4 & 2u)) x.y = 0.f;
      if (!(b4 & 4u)) x.z = 0.f;
      if (!(b4 & 8u)) x.w = 0.f;
      v[j] = x;
      am = fmaxf(am, fmaxf(fmaxf(fabsf(x.x), fabsf(x.y)), fmaxf(fabsf(x.z), fabsf(x.w))));
    }
#pragma unroll
    for (int m = 1; m < 64; m <<= 1) am = fmaxf(am, __shfl_xor(am, m));
    const _Float16 sh = (_Float16)(am / 127.0f);   // RTN to fp16, like astype(float16)
    const float inv = 1.0f / (float)sh;            // one exact divide per row
    if (lane == 0) { if (isW) wmax[r] = sh; else xmax[r - N] = sh; }
    signed char* rowq = qt + w * 4096;
#pragma unroll
    for (int j = 0; j < 16; ++j) {
      float4 x = v[j];
      char4 c;
      c.x = (signed char)(x.x * inv);    // rcp-mul + trunc (audited: <=1ulp vs div)
      c.y = (signed char)(x.y * inv);
      c.z = (signed char)(x.z * inv);
      c.w = (signed char)(x.w * inv);
      const int c2 = j * 16 + (lane >> 2);
      *(char4*)(rowq + ((c2 ^ w) << 4) + (lane & 3) * 4) = c;   // 2-way max (free)
    }
    __syncthreads();
    // store phase: 1024 int4 (4 rows x 256 chunks), 128B-contiguous segments
#pragma unroll
    for (int i = 0; i < 4; ++i) {
      const int s2 = i * 256 + t;
      const int c2 = s2 >> 2, rl = s2 & 3;
      const int row = r0 + g * 4 + rl;                 // never straddles a 32-panel
      int4 d = *(const int4*)(qt + rl * 4096 + ((c2 ^ rl) << 4));
      signed char* q = (row < N) ? wq : xq;
      const int rr = (row < N) ? row : row - N;
      *(int4*)(q + (size_t)(rr >> 5) * 32 * K + (size_t)c2 * 512 + (rr & 31) * 16) = d;
    }
    __syncthreads();
  }
  // outlier gather: 32 idx x 12 rows = 384 scattered floats
  for (int p = t; p < 32 * 12; p += 256) {
    const int lr = p >> 5, j = p & 31;
    const int row = r0 + lr;
    if (row < N) wuf[(size_t)j * N + row]       = srcW[(size_t)row * K + idxg[j]];
    else         xuf[(size_t)j * M + (row - N)] = srcX[(size_t)(row - N) * K + idxg[j]];
  }
}

// ---- kernel D: i8 GEMM, 128x128 WAVE-TILE (4 waves, 256x256 block, acc 4x4).
//      Cuts LDS reads/MFMA from 768B to 512B -- LDS pipe (was 51% busy,
//      serialized with matrix) drops below matrix demand. Ring-2 LDS, 8 DMA
//      issues/tile, 1-tile lead; vmcnt(0) at top is counted-by-construction.
__device__ __forceinline__ void gld_lds16(const signed char* g, signed char* l) {
  __builtin_amdgcn_global_load_lds(
      (const __attribute__((address_space(1))) void*)g,
      (__attribute__((address_space(3))) void*)l, 16, 0, 0);
}

__global__ __launch_bounds__(256, 1) void gemm_kernel(
    const signed char* __restrict__ xq, const signed char* __restrict__ wq,
    const _Float16* __restrict__ xmax, const _Float16* __restrict__ wmax,
    const float* __restrict__ xuf,   // [ALPHA][M]
    const float* __restrict__ wuf,   // [ALPHA][N]
    const float* __restrict__ bias,  // [N]
    float* __restrict__ out, int M, int N, int K) {
  __shared__ union {
    struct { signed char A[2][BM * BK]; signed char B[2][BN * BK]; } g;  // 64 KB ring-2
    struct { float xu[ALPHA * BM]; float wu[ALPHA * BN]; } e;            // 64 KB
  } sm;
  __shared__ _Float16 xmh[BM];
  __shared__ _Float16 wmh[BN];
  __shared__ float    bl[BN];

  const int t = threadIdx.x;
  // XCD-aware swizzle: 512 blocks, 8 XCDs -> each XCD owns 2 bx columns.
  const int bid = blockIdx.y * gridDim.x + blockIdx.x;
  const int xcd = bid & 7, loc = bid >> 3;
  const int bxi = xcd * 2 + (loc & 1);
  const int byi = loc >> 1;
  const int bm0 = byi * BM;
  const int bn0 = bxi * BN;
  const int lane = t & 63, w = t >> 6;
  const int wm = w >> 1, wn = w & 1;       // 2x2 waves, wave tile 128x128
  const int hi = lane >> 5, l31 = lane & 31;

  i32x16 acc[4][4] = {};

  const size_t P32 = (size_t)32 * K;
  const signed char* aS = xq + (size_t)bm0 * K + (size_t)(t >> 7) * P32 + (t & 127) * 16;
  const signed char* bS = wq + (size_t)bn0 * K + (size_t)(t >> 7) * P32 + (t & 127) * 16;
  signed char* const aD = &sm.g.A[0][0] + t * 16;
  signed char* const bD = &sm.g.B[0][0] + t * 16;
  const signed char* const aR0 = &sm.g.A[0][0] + (wm * 4) * 2048 + hi * 512 + l31 * 16;
  const signed char* const bR0 = &sm.g.B[0][0] + (wn * 4) * 2048 + hi * 512 + l31 * 16;

  auto STAGE = [&](int buf, int kt) {
    const size_t ko = (size_t)kt * 2048;
#pragma unroll
    for (int i = 0; i < 4; ++i)
      gld_lds16(aS + (size_t)(2 * i) * P32 + ko, aD + buf * 16384 + i * 4096);
#pragma unroll
    for (int i = 0; i < 4; ++i)
      gld_lds16(bS + (size_t)(2 * i) * P32 + ko, bD + buf * 16384 + i * 4096);
  };

  const int NT = K >> 6;   // 64
  STAGE(0, 0);
  for (int kt = 0; kt < NT; ++kt) {
    const int cur = kt & 1;
    asm volatile("s_waitcnt vmcnt(0)" ::: "memory");   // S(kt): only outstanding
    asm volatile("s_barrier" ::: "memory");
    const signed char* aRd = aR0 + cur * 16384;
    const signed char* bRd = bR0 + cur * 16384;
    i32x4 af0[4], bf0[4], af1[4], bf1[4];
#pragma unroll
    for (int mi = 0; mi < 4; ++mi) af0[mi] = *(const i32x4*)(aRd + mi * 2048);
#pragma unroll
    for (int ni = 0; ni < 4; ++ni) bf0[ni] = *(const i32x4*)(bRd + ni * 2048);
#pragma unroll
    for (int mi = 0; mi < 4; ++mi) af1[mi] = *(const i32x4*)(aRd + mi * 2048 + 1024);
#pragma unroll
    for (int ni = 0; ni < 4; ++ni) bf1[ni] = *(const i32x4*)(bRd + ni * 2048 + 1024);
    if (kt + 1 < NT) STAGE(cur ^ 1, kt + 1);   // flies under the 32-MFMA cluster
#pragma unroll
    for (int mi = 0; mi < 4; ++mi)
#pragma unroll
      for (int ni = 0; ni < 4; ++ni)
        acc[mi][ni] = __builtin_amdgcn_mfma_i32_32x32x32_i8(af0[mi], bf0[ni], acc[mi][ni], 0, 0, 0);
#pragma unroll
    for (int mi = 0; mi < 4; ++mi)
#pragma unroll
      for (int ni = 0; ni < 4; ++ni)
        acc[mi][ni] = __builtin_amdgcn_mfma_i32_32x32x32_i8(af1[mi], bf1[ni], acc[mi][ni], 0, 0, 0);
  }

  __syncthreads();
  // ---- epilogue staging (reuses GEMM LDS) ----
  {
    const float4* xs = (const float4*)xuf;
    float4* xl = (float4*)sm.e.xu;
#pragma unroll
    for (int i = 0; i < 8; ++i) {   // 2048 float4
      int p = i * 256 + t;
      int j = p >> 6, r4 = p & 63;
      xl[p] = xs[(size_t)j * (M >> 2) + (bm0 >> 2) + r4];
    }
    const float4* wsrc = (const float4*)wuf;
    float4* wl = (float4*)sm.e.wu;
#pragma unroll
    for (int i = 0; i < 8; ++i) {   // 2048 float4
      int p = i * 256 + t;
      int j = p >> 6, r4 = p & 63;
      wl[p] = wsrc[(size_t)j * (N >> 2) + (bn0 >> 2) + r4];
    }
    if (t < BM / 2) ((unsigned*)xmh)[t] = ((const unsigned*)(xmax + bm0))[t];
    if (t < BN / 2) ((unsigned*)wmh)[t] = ((const unsigned*)(wmax + bn0))[t];
    if (t < BN / 4) ((float4*)bl)[t] = ((const float4*)(bias + bn0))[t];
  }
  __syncthreads();

  const int c0 = wn * 128 + l31;   // column (within tile) for ni=0; +32 per ni
  _Float16 wh[4]; float bv[4];
#pragma unroll
  for (int ni = 0; ni < 4; ++ni) { wh[ni] = wmh[c0 + ni * 32]; bv[ni] = bl[c0 + ni * 32]; }
  const float* xul = sm.e.xu;     // [ALPHA][BM]
  const float* wul = sm.e.wu;     // [ALPHA][BN]

#pragma unroll
  for (int mi = 0; mi < 4; ++mi) {
    const int rbase = wm * 128 + mi * 32 + 4 * hi;   // + (r&3) + 8*(r>>2)
    float f[4][16];
#pragma unroll
    for (int r = 0; r < 16; ++r) {
      int row = rbase + (r & 3) + 8 * (r >> 2);
      _Float16 xh = xmh[row];
#pragma unroll
      for (int ni = 0; ni < 4; ++ni) {
        float mx = (float)(_Float16)(xh * wh[ni]);   // fp16 multiply like ref
        f[ni][r] = (float)acc[mi][ni][r] * mx + bv[ni];
      }
    }
#pragma unroll 4
    for (int j = 0; j < ALPHA; ++j) {            // rank-32 fp32 outlier update
      const float4* xrow4 = (const float4*)(xul + j * BM + rbase);
      float wv[4];
#pragma unroll
      for (int ni = 0; ni < 4; ++ni) wv[ni] = wul[j * BN + c0 + ni * 32];
#pragma unroll
      for (int gq = 0; gq < 4; ++gq) {
        float4 xv = xrow4[gq * 2];               // rows rbase + 8*gq .. +3
#pragma unroll
        for (int ni = 0; ni < 4; ++ni) {
          f[ni][gq * 4 + 0] += xv.x * wv[ni];
          f[ni][gq * 4 + 1] += xv.y * wv[ni];
          f[ni][gq * 4 + 2] += xv.z * wv[ni];
          f[ni][gq * 4 + 3] += xv.w * wv[ni];
        }
      }
    }
#pragma unroll
    for (int r = 0; r < 16; ++r) {
      int row = bm0 + rbase + (r & 3) + 8 * (r >> 2);
      size_t o = (size_t)row * N + bn0;
#pragma unroll
      for (int ni = 0; ni < 4; ++ni) out[o + c0 + ni * 32] = f[ni][r];
    }
  }
}

// ---------------- launch ----------------
extern "C" void kernel_launch(void* const* d_in, const int* in_sizes, int n_in,
                              void* d_out, int out_size, void* d_ws, size_t ws_size,
                              hipStream_t stream) {
  const float* x       = (const float*)d_in[0];
  const float* W       = (const float*)d_in[1];
  const float* bias    = (const float*)d_in[2];
  const float* act_max = (const float*)d_in[3];
  const int K = in_sizes[3];            // 4096
  const int N = in_sizes[1] / K;        // 4096
  const int M = in_sizes[0] / K;        // 8192
  float* out = (float*)d_out;

  char* ws = (char*)d_ws;
  size_t off = 0;
  auto take = [&](size_t b) { char* p = ws + off; off += (b + 255) & ~(size_t)255; return p; };
  signed char* wq  = (signed char*)take((size_t)N * K);
  signed char* xq  = (signed char*)take((size_t)M * K);
  _Float16* wmax   = (_Float16*)take((size_t)N * 2);
  _Float16* xmax   = (_Float16*)take((size_t)M * 2);
  float* wuf       = (float*)take((size_t)ALPHA * N * 4);
  float* xuf       = (float*)take((size_t)ALPHA * M * 4);
  int* idx         = (int*)take(ALPHA * 4);
  unsigned* tbits  = (unsigned*)take((size_t)(K / 32) * 4);

  topk_kernel<<<1, 256, 0, stream>>>(act_max, idx, tbits, K);
  quant12_kernel<<<(N + M) / 12, 256, 0, stream>>>(W, x, tbits, idx, wq, xq,
                                                   wmax, xmax, wuf, xuf, K, N, M);
  dim3 grid(N / BN, M / BM);
  gemm_kernel<<<grid, 256, 0, stream>>>(xq, wq, xmax, wmax, xuf, wuf, bias, out, M, N, K);
}

// Round 13
// 255.310 us; speedup vs baseline: 1.0399x; 1.0399x over previous
//
#include <hip/hip_runtime.h>
#include <hip/hip_fp16.h>

typedef __attribute__((ext_vector_type(4)))  int   i32x4;
typedef __attribute__((ext_vector_type(16))) int   i32x16;

#define ALPHA 32
#define BM 256
#define BN 128
#define BK 64

// Tiled int8 workspace layout (matches LDS staging & fragment reads):
//   addr(row,k) = (row>>5)*(32*K) + (k>>4)*512 + (row&31)*16 + (k&15)

// ---------------- kernel A: top-32 of |act_max| + keep-bitmask ----------------
__global__ __launch_bounds__(256) void topk_kernel(const float* __restrict__ act_max,
                                                   int* __restrict__ idx_out,
                                                   unsigned* __restrict__ tbits,
                                                   int K) {
  __shared__ float rv[4];
  __shared__ int   ri[4];
  __shared__ unsigned bits[128];
  __shared__ int bsel;
  const int t = threadIdx.x, w = t >> 6;
  float vloc[16];
#pragma unroll
  for (int jj = 0; jj < 16; ++jj) vloc[jj] = fabsf(act_max[jj * 256 + t]);
  for (int i = t; i < 128; i += 256) bits[i] = 0xFFFFFFFFu;
  __syncthreads();
  for (int sel = 0; sel < ALPHA; ++sel) {
    float bv = vloc[0]; int bi = t;          // ascending scan keeps lowest index on ties
#pragma unroll
    for (int jj = 1; jj < 16; ++jj)
      if (vloc[jj] > bv) { bv = vloc[jj]; bi = jj * 256 + t; }
    for (int m = 1; m < 64; m <<= 1) {
      float ov = __shfl_xor(bv, m);
      int   oi = __shfl_xor(bi, m);
      if (ov > bv || (ov == bv && oi < bi)) { bv = ov; bi = oi; }
    }
    if ((t & 63) == 0) { rv[w] = bv; ri[w] = bi; }
    __syncthreads();
    if (t == 0) {
      for (int u = 1; u < 4; ++u)
        if (rv[u] > bv || (rv[u] == bv && ri[u] < bi)) { bv = rv[u]; bi = ri[u]; }
      idx_out[sel] = bi;
      bits[bi >> 5] &= ~(1u << (bi & 31));
      bsel = bi;
    }
    __syncthreads();
    const int bs = bsel;
#pragma unroll
    for (int jj = 0; jj < 16; ++jj)
      if (jj * 256 + t == bs) vloc[jj] = -2.f;
    __syncthreads();
  }
  for (int i = t; i < 128; i += 256) tbits[i] = bits[i];
}

// ------------- kernel B: 16-rows-per-block quantization + gather -------------
// 768 blocks (all resident, one round, zero tail); each block entirely in W or
// X. 4 phases of 4 rows (one row/wave); store every 8 rows so tiled stores are
// full 128B-contiguous segments (c2=s2>>3, rl=s2&7).
__global__ __launch_bounds__(256) void quant16_kernel(
    const float* __restrict__ srcW, const float* __restrict__ srcX,
    const unsigned* __restrict__ tbits, const int* __restrict__ idxg,
    signed char* __restrict__ wq, signed char* __restrict__ xq,
    _Float16* __restrict__ wmax, _Float16* __restrict__ xmax,
    float* __restrict__ wuf, float* __restrict__ xuf,
    int K, int N, int M) {
  const int t = threadIdx.x, lane = t & 63, w = t >> 6;
  const int b = blockIdx.x;
  const int nbw = N >> 4;                       // W blocks first
  const bool isW = b < nbw;
  const float* src = isW ? srcW : srcX;
  signed char* q   = isW ? wq : xq;
  _Float16* smax   = isW ? wmax : xmax;
  float* unq       = isW ? wuf : xuf;
  const int R      = isW ? N : M;
  const int r0     = (isW ? b : b - nbw) * 16;  // local row base
  __shared__ unsigned bits[128];
  __shared__ signed char qt[8 * 4096];          // 32 KB bounce (8 rows/half)
  for (int i = t; i < 128; i += 256) bits[i] = tbits[i];
  __syncthreads();
  const int shft = (lane & 7) * 4;
#pragma unroll
  for (int hf = 0; hf < 2; ++hf) {
#pragma unroll
    for (int gg = 0; gg < 2; ++gg) {
      const int rl8 = gg * 4 + w;               // slot in the 8-row half
      const int r = r0 + hf * 8 + rl8;          // this wave's local row
      const float4* srow4 = (const float4*)(src + (size_t)r * K);
      float4 v[16];
      float am = 0.f;
#pragma unroll
      for (int j = 0; j < 16; ++j) {            // wave reads 1KB contiguous per instr
        float4 x = srow4[j * 64 + lane];
        unsigned b4 = bits[j * 8 + (lane >> 3)] >> shft;
        if (!(b4 & 1u)) x.x = 0.f;
        if (!(b4 & 2u)) x.y = 0.f;
        if (!(b4 & 4u)) x.z = 0.f;
        if (!(b4 & 8u)) x.w = 0.f;
        v[j] = x;
        am = fmaxf(am, fmaxf(fmaxf(fabsf(x.x), fabsf(x.y)), fmaxf(fabsf(x.z), fabsf(x.w))));
      }
#pragma unroll
      for (int m = 1; m < 64; m <<= 1) am = fmaxf(am, __shfl_xor(am, m));
      const _Float16 sh = (_Float16)(am / 127.0f);   // RTN to fp16, like astype(float16)
      const float inv = 1.0f / (float)sh;            // one exact divide per row
      if (lane == 0) smax[r] = sh;
      signed char* rowq = qt + rl8 * 4096;
#pragma unroll
      for (int j = 0; j < 16; ++j) {
        float4 x = v[j];
        char4 c;
        c.x = (signed char)(x.x * inv);   // rcp-mul + trunc (<=1ulp vs div, audited r11)
        c.y = (signed char)(x.y * inv);
        c.z = (signed char)(x.z * inv);
        c.w = (signed char)(x.w * inv);
        const int c2 = j * 16 + (lane >> 2);
        *(char4*)(rowq + ((c2 ^ rl8) << 4) + (lane & 3) * 4) = c;
      }
    }
    __syncthreads();
    // store half: 2048 int4, full 128B-contiguous segments (8 rows x 16B)
#pragma unroll
    for (int i = 0; i < 8; ++i) {
      const int s2 = i * 256 + t;
      const int c2 = s2 >> 3, rl = s2 & 7;
      const int rr = r0 + hf * 8 + rl;          // 16-row block never straddles a panel
      int4 d = *(const int4*)(qt + rl * 4096 + ((c2 ^ rl) << 4));
      *(int4*)(q + (size_t)(rr >> 5) * 32 * K + (size_t)c2 * 512 + (rr & 31) * 16) = d;
    }
    __syncthreads();
  }
  // outlier gather: 32 idx x 16 rows = 512 scattered floats
#pragma unroll
  for (int i = 0; i < 2; ++i) {
    const int p = i * 256 + t;
    const int lr = p >> 5, j = p & 31;
    unq[(size_t)j * R + r0 + lr] = src[(size_t)(r0 + lr) * K + idxg[j]];
  }
}

// ---- kernel D: i8 GEMM (round-5 verbatim: 3-buf ring, 2-deep prefetch,
//      counted vmcnt(6), peeled tail, setprio) -- measured 178 us / 37%.
//      FROZEN: 7 structure variants (r4-r12) all land 177-228; this is the min.
__device__ __forceinline__ void gld_lds16(const signed char* g, signed char* l) {
  __builtin_amdgcn_global_load_lds(
      (const __attribute__((address_space(1))) void*)g,
      (__attribute__((address_space(3))) void*)l, 16, 0, 0);
}

__global__ __launch_bounds__(256, 2) void gemm_kernel(
    const signed char* __restrict__ xq, const signed char* __restrict__ wq,
    const _Float16* __restrict__ xmax, const _Float16* __restrict__ wmax,
    const float* __restrict__ xuf,   // [ALPHA][M]
    const float* __restrict__ wuf,   // [ALPHA][N]
    const float* __restrict__ bias,  // [N]
    float* __restrict__ out, int M, int N, int K) {
  __shared__ union {
    struct { signed char A[3][BM * BK]; signed char B[3][BN * BK]; } g;  // 72 KB, 3-buf
    struct { float xu[ALPHA * BM]; float wu[ALPHA * BN]; } e;            // 48 KB
  } sm;
  __shared__ _Float16 xmh[BM];
  __shared__ _Float16 wmh[BN];
  __shared__ float    bl[BN];

  const int t = threadIdx.x;
  // XCD-aware swizzle: 1024 blocks, 8 XCDs -> each XCD owns 4 consecutive bx.
  const int bid = blockIdx.y * gridDim.x + blockIdx.x;
  const int xcd = bid & 7, loc = bid >> 3;
  const int bxi = xcd * 4 + (loc & 3);
  const int byi = loc >> 2;
  const int bm0 = byi * BM;
  const int bn0 = bxi * BN;
  const int lane = t & 63, w = t >> 6;
  const int wm = w >> 1, wn = w & 1;       // 2x2 waves, wave tile 128x64
  const int hi = lane >> 5, l31 = lane & 31;

  i32x16 acc[4][2] = {};

  const int tp = t >> 7;                  // panel parity within an issue
  const int to = (t & 127) * 16;
  const signed char* aS = xq + (size_t)bm0 * K + (size_t)tp * 32 * K + to;
  const signed char* bS = wq + (size_t)bn0 * K + (size_t)tp * 32 * K + to;
  signed char* const aD = &sm.g.A[0][0] + t * 16;
  signed char* const bD = &sm.g.B[0][0] + t * 16;
  const size_t PSTR = (size_t)64 * K;     // 2-panel stride

  auto STAGE = [&](int buf, int kt) {
    const size_t ko = (size_t)kt * 2048;  // (kt*64)>>4 * 512
#pragma unroll
    for (int i = 0; i < 4; ++i)
      gld_lds16(aS + (size_t)i * PSTR + ko, aD + buf * (BM * BK) + i * 4096);
#pragma unroll
    for (int i = 0; i < 2; ++i)
      gld_lds16(bS + (size_t)i * PSTR + ko, bD + buf * (BN * BK) + i * 4096);
  };

  const int NT = K >> 6;   // 64
  STAGE(0, 0);
  STAGE(1, 1);
  const signed char* const aR0 = &sm.g.A[0][0] + (wm * 4) * 2048 + 16 * lane;
  const signed char* const bR0 = &sm.g.B[0][0] + (wn * 2) * 2048 + 16 * lane;

  int cur = 0, st = 2;
  for (int kt = 0; kt < NT - 1; ++kt) {
    // tile kt's loads were issued 2 iters ago: counted wait, never drain to 0.
    asm volatile("s_waitcnt vmcnt(6)" ::: "memory");
    asm volatile("s_barrier" ::: "memory");
    const signed char* aRd = aR0 + cur * (BM * BK);
    const signed char* bRd = bR0 + cur * (BN * BK);
    i32x4 af[2][4], bf[2][2];
#pragma unroll
    for (int ks = 0; ks < 2; ++ks) {
#pragma unroll
      for (int mi = 0; mi < 4; ++mi) af[ks][mi] = *(const i32x4*)(aRd + mi * 2048 + ks * 1024);
#pragma unroll
      for (int ni = 0; ni < 2; ++ni) bf[ks][ni] = *(const i32x4*)(bRd + ni * 2048 + ks * 1024);
    }
    if (kt + 2 < NT) STAGE(st, kt + 2);   // 2-deep prefetch
    __builtin_amdgcn_s_setprio(1);
#pragma unroll
    for (int ks = 0; ks < 2; ++ks)
#pragma unroll
      for (int mi = 0; mi < 4; ++mi)
#pragma unroll
        for (int ni = 0; ni < 2; ++ni)
          acc[mi][ni] = __builtin_amdgcn_mfma_i32_32x32x32_i8(af[ks][mi], bf[ks][ni], acc[mi][ni], 0, 0, 0);
    __builtin_amdgcn_s_setprio(0);
    if (++cur == 3) cur = 0;
    if (++st == 3) st = 0;
  }
  { // peeled last tile: only here do we drain
    asm volatile("s_waitcnt vmcnt(0)" ::: "memory");
    asm volatile("s_barrier" ::: "memory");
    const signed char* aRd = aR0 + cur * (BM * BK);
    const signed char* bRd = bR0 + cur * (BN * BK);
    i32x4 af[2][4], bf[2][2];
#pragma unroll
    for (int ks = 0; ks < 2; ++ks) {
#pragma unroll
      for (int mi = 0; mi < 4; ++mi) af[ks][mi] = *(const i32x4*)(aRd + mi * 2048 + ks * 1024);
#pragma unroll
      for (int ni = 0; ni < 2; ++ni) bf[ks][ni] = *(const i32x4*)(bRd + ni * 2048 + ks * 1024);
    }
    __builtin_amdgcn_s_setprio(1);
#pragma unroll
    for (int ks = 0; ks < 2; ++ks)
#pragma unroll
      for (int mi = 0; mi < 4; ++mi)
#pragma unroll
        for (int ni = 0; ni < 2; ++ni)
          acc[mi][ni] = __builtin_amdgcn_mfma_i32_32x32x32_i8(af[ks][mi], bf[ks][ni], acc[mi][ni], 0, 0, 0);
    __builtin_amdgcn_s_setprio(0);
  }

  __syncthreads();
  // ---- epilogue staging (reuses GEMM LDS) ----
  {
    const float4* xs = (const float4*)xuf;
    float4* xl = (float4*)sm.e.xu;
#pragma unroll
    for (int i = 0; i < 8; ++i) {   // 2048 float4
      int p = i * 256 + t;
      int j = p >> 6, r4 = p & 63;
      xl[p] = xs[(size_t)j * (M >> 2) + (bm0 >> 2) + r4];
    }
    const float4* wsrc = (const float4*)wuf;
    float4* wl = (float4*)sm.e.wu;
#pragma unroll
    for (int i = 0; i < 4; ++i) {   // 1024 float4
      int p = i * 256 + t;
      int j = p >> 5, r4 = p & 31;
      wl[p] = wsrc[(size_t)j * (N >> 2) + (bn0 >> 2) + r4];
    }
    if (t < BM / 2) ((unsigned*)xmh)[t] = ((const unsigned*)(xmax + bm0))[t];
    if (t < BN / 2) ((unsigned*)wmh)[t] = ((const unsigned*)(wmax + bn0))[t];
    if (t < BN / 4) ((float4*)bl)[t] = ((const float4*)(bias + bn0))[t];
  }
  __syncthreads();

  const int c0 = wn * 64 + l31;   // column (within tile) for ni=0; ni=1 is +32
  const _Float16 wh0 = wmh[c0], wh1 = wmh[c0 + 32];
  const float bv0 = bl[c0], bv1 = bl[c0 + 32];
  const float* xul = sm.e.xu;     // [ALPHA][BM]
  const float* wul = sm.e.wu;     // [ALPHA][BN]

#pragma unroll
  for (int mi = 0; mi < 4; ++mi) {
    const int rbase = wm * 128 + mi * 32 + 4 * hi;   // + (r&3) + 8*(r>>2)
    float f0[16], f1[16];
#pragma unroll
    for (int r = 0; r < 16; ++r) {
      int row = rbase + (r & 3) + 8 * (r >> 2);
      _Float16 xh = xmh[row];
      float mx0 = (float)(_Float16)(xh * wh0);   // fp16 multiply (subnormal-correct) like ref
      float mx1 = (float)(_Float16)(xh * wh1);
      f0[r] = (float)acc[mi][0][r] * mx0 + bv0;
      f1[r] = (float)acc[mi][1][r] * mx1 + bv1;
    }
#pragma unroll 4
    for (int j = 0; j < ALPHA; ++j) {            // rank-32 fp32 outlier update
      const float4* xrow4 = (const float4*)(xul + j * BM + rbase);
      float wv0 = wul[j * BN + c0];
      float wv1 = wul[j * BN + c0 + 32];
#pragma unroll
      for (int gq = 0; gq < 4; ++gq) {
        float4 xv = xrow4[gq * 2];               // rows rbase + 8*gq .. +3
        f0[gq * 4 + 0] += xv.x * wv0;  f1[gq * 4 + 0] += xv.x * wv1;
        f0[gq * 4 + 1] += xv.y * wv0;  f1[gq * 4 + 1] += xv.y * wv1;
        f0[gq * 4 + 2] += xv.z * wv0;  f1[gq * 4 + 2] += xv.z * wv1;
        f0[gq * 4 + 3] += xv.w * wv0;  f1[gq * 4 + 3] += xv.w * wv1;
      }
    }
#pragma unroll
    for (int r = 0; r < 16; ++r) {
      int row = bm0 + rbase + (r & 3) + 8 * (r >> 2);
      size_t o = (size_t)row * N + bn0;
      out[o + c0] = f0[r];
      out[o + c0 + 32] = f1[r];
    }
  }
}

// ---------------- launch ----------------
extern "C" void kernel_launch(void* const* d_in, const int* in_sizes, int n_in,
                              void* d_out, int out_size, void* d_ws, size_t ws_size,
                              hipStream_t stream) {
  const float* x       = (const float*)d_in[0];
  const float* W       = (const float*)d_in[1];
  const float* bias    = (const float*)d_in[2];
  const float* act_max = (const float*)d_in[3];
  const int K = in_sizes[3];            // 4096
  const int N = in_sizes[1] / K;        // 4096
  const int M = in_sizes[0] / K;        // 8192
  float* out = (float*)d_out;

  char* ws = (char*)d_ws;
  size_t off = 0;
  auto take = [&](size_t b) { char* p = ws + off; off += (b + 255) & ~(size_t)255; return p; };
  signed char* wq  = (signed char*)take((size_t)N * K);
  signed char* xq  = (signed char*)take((size_t)M * K);
  _Float16* wmax   = (_Float16*)take((size_t)N * 2);
  _Float16* xmax   = (_Float16*)take((size_t)M * 2);
  float* wuf       = (float*)take((size_t)ALPHA * N * 4);
  float* xuf       = (float*)take((size_t)ALPHA * M * 4);
  int* idx         = (int*)take(ALPHA * 4);
  unsigned* tbits  = (unsigned*)take((size_t)(K / 32) * 4);

  topk_kernel<<<1, 256, 0, stream>>>(act_max, idx, tbits, K);
  quant16_kernel<<<(N + M) / 16, 256, 0, stream>>>(W, x, tbits, idx, wq, xq,
                                                   wmax, xmax, wuf, xuf, K, N, M);
  dim3 grid(N / BN, M / BM);
  gemm_kernel<<<grid, 256, 0, stream>>>(xq, wq, xmax, wmax, xuf, wuf, bias, out, M, N, K);
}

// Round 14
// 252.439 us; speedup vs baseline: 1.0517x; 1.0114x over previous
//
#include <hip/hip_runtime.h>
#include <hip/hip_fp16.h>

typedef __attribute__((ext_vector_type(4)))  int   i32x4;
typedef __attribute__((ext_vector_type(16))) int   i32x16;

#define ALPHA 32
#define BM 256
#define BN 128
#define BK 64

// Tiled int8 workspace layout (matches LDS staging & fragment reads):
//   addr(row,k) = (row>>5)*(32*K) + (k>>4)*512 + (row&31)*16 + (k&15)

// ---------------- kernel A: top-32 of |act_max| + keep-bitmask ----------------
__global__ __launch_bounds__(256) void topk_kernel(const float* __restrict__ act_max,
                                                   int* __restrict__ idx_out,
                                                   unsigned* __restrict__ tbits,
                                                   int K) {
  __shared__ float rv[4];
  __shared__ int   ri[4];
  __shared__ unsigned bits[128];
  __shared__ int bsel;
  const int t = threadIdx.x, w = t >> 6;
  float vloc[16];
#pragma unroll
  for (int jj = 0; jj < 16; ++jj) vloc[jj] = fabsf(act_max[jj * 256 + t]);
  for (int i = t; i < 128; i += 256) bits[i] = 0xFFFFFFFFu;
  __syncthreads();
  for (int sel = 0; sel < ALPHA; ++sel) {
    float bv = vloc[0]; int bi = t;          // ascending scan keeps lowest index on ties
#pragma unroll
    for (int jj = 1; jj < 16; ++jj)
      if (vloc[jj] > bv) { bv = vloc[jj]; bi = jj * 256 + t; }
    for (int m = 1; m < 64; m <<= 1) {
      float ov = __shfl_xor(bv, m);
      int   oi = __shfl_xor(bi, m);
      if (ov > bv || (ov == bv && oi < bi)) { bv = ov; bi = oi; }
    }
    if ((t & 63) == 0) { rv[w] = bv; ri[w] = bi; }
    __syncthreads();
    if (t == 0) {
      for (int u = 1; u < 4; ++u)
        if (rv[u] > bv || (rv[u] == bv && ri[u] < bi)) { bv = rv[u]; bi = ri[u]; }
      idx_out[sel] = bi;
      bits[bi >> 5] &= ~(1u << (bi & 31));
      bsel = bi;
    }
    __syncthreads();
    const int bs = bsel;
#pragma unroll
    for (int jj = 0; jj < 16; ++jj)
      if (jj * 256 + t == bs) vloc[jj] = -2.f;
    __syncthreads();
  }
  for (int i = t; i < 128; i += 256) tbits[i] = bits[i];
}

// ------------- kernel B: 16-rows-per-block quantization, T14-pipelined -------
// LOAD (pure global->reg) split from PROC (mask+reduce+quantize+LDS); rows are
// software-pipelined L0 L1 P0 L2 P1 L3 | store0 | P2 P3 | store1 so HBM latency
// of rows 1..3 hides under PROC/store work. 768 blocks, one resident round.
__global__ __launch_bounds__(256) void quant16_kernel(
    const float* __restrict__ srcW, const float* __restrict__ srcX,
    const unsigned* __restrict__ tbits, const int* __restrict__ idxg,
    signed char* __restrict__ wq, signed char* __restrict__ xq,
    _Float16* __restrict__ wmax, _Float16* __restrict__ xmax,
    float* __restrict__ wuf, float* __restrict__ xuf,
    int K, int N, int M) {
  const int t = threadIdx.x, lane = t & 63, w = t >> 6;
  const int b = blockIdx.x;
  const int nbw = N >> 4;                       // W blocks first
  const bool isW = b < nbw;
  const float* src = isW ? srcW : srcX;
  signed char* q   = isW ? wq : xq;
  _Float16* smax   = isW ? wmax : xmax;
  float* unq       = isW ? wuf : xuf;
  const int R      = isW ? N : M;
  const int r0     = (isW ? b : b - nbw) * 16;  // local row base
  __shared__ unsigned bits[128];
  __shared__ signed char qt[8 * 4096];          // 32 KB bounce (8 rows/half)
  for (int i = t; i < 128; i += 256) bits[i] = tbits[i];
  __syncthreads();
  const int shft = (lane & 7) * 4;

  const float4* row0 = (const float4*)(src + (size_t)(r0 + w) * K);
  const float4* row1 = (const float4*)(src + (size_t)(r0 + 4 + w) * K);
  const float4* row2 = (const float4*)(src + (size_t)(r0 + 8 + w) * K);
  const float4* row3 = (const float4*)(src + (size_t)(r0 + 12 + w) * K);
  float4 vA[16], vB[16];

#define LOADR(V, ROWP)                                                          \
  _Pragma("unroll") for (int j = 0; j < 16; ++j) V[j] = ROWP[j * 64 + lane];

#define PROCR(V, ROWOFF)                                                        \
  {                                                                             \
    float am = 0.f;                                                             \
    _Pragma("unroll") for (int j = 0; j < 16; ++j) {                            \
      float4 x = V[j];                                                          \
      unsigned b4 = bits[j * 8 + (lane >> 3)] >> shft;                          \
      if (!(b4 & 1u)) x.x = 0.f;                                                \
      if (!(b4 & 2u)) x.y = 0.f;                                                \
      if (!(b4 & 4u)) x.z = 0.f;                                                \
      if (!(b4 & 8u)) x.w = 0.f;                                                \
      V[j] = x;                                                                 \
      am = fmaxf(am, fmaxf(fmaxf(fabsf(x.x), fabsf(x.y)),                       \
                           fmaxf(fabsf(x.z), fabsf(x.w))));                     \
    }                                                                           \
    _Pragma("unroll") for (int m = 1; m < 64; m <<= 1)                          \
      am = fmaxf(am, __shfl_xor(am, m));                                        \
    const _Float16 sh = (_Float16)(am / 127.0f);  /* RTN fp16 like ref */       \
    const float inv = 1.0f / (float)sh;           /* one exact divide/row */    \
    if (lane == 0) smax[r0 + (ROWOFF)] = sh;                                    \
    signed char* rowq = qt + ((ROWOFF) & 7) * 4096;                             \
    _Pragma("unroll") for (int j = 0; j < 16; ++j) {                            \
      float4 x = V[j];                                                          \
      char4 c;                                                                  \
      c.x = (signed char)(x.x * inv);  /* rcp-mul+trunc, <=1ulp vs div (r11) */ \
      c.y = (signed char)(x.y * inv);                                           \
      c.z = (signed char)(x.z * inv);                                           \
      c.w = (signed char)(x.w * inv);                                           \
      const int c2 = j * 16 + (lane >> 2);                                      \
      *(char4*)(rowq + ((c2 ^ ((ROWOFF) & 7)) << 4) + (lane & 3) * 4) = c;      \
    }                                                                           \
  }

#define STOREHALF(HBASE)                                                        \
  _Pragma("unroll") for (int i = 0; i < 8; ++i) {                               \
    const int s2 = i * 256 + t;                                                 \
    const int c2 = s2 >> 3, rl = s2 & 7;                                        \
    const int rr = r0 + (HBASE) + rl;                                           \
    int4 d = *(const int4*)(qt + rl * 4096 + ((c2 ^ rl) << 4));                 \
    *(int4*)(q + (size_t)(rr >> 5) * 32 * K + (size_t)c2 * 512 +                \
             (rr & 31) * 16) = d;                                               \
  }

  LOADR(vA, row0);
  LOADR(vB, row1);
  PROCR(vA, w);
  LOADR(vA, row2);          // issued early: latency hides under P1 + store0
  PROCR(vB, 4 + w);
  LOADR(vB, row3);
  __syncthreads();
  STOREHALF(0);
  __syncthreads();
  PROCR(vA, 8 + w);
  PROCR(vB, 12 + w);
  __syncthreads();
  STOREHALF(8);
#undef STOREHALF
#undef PROCR
#undef LOADR

  // outlier gather: 32 idx x 16 rows = 512 scattered floats
#pragma unroll
  for (int i = 0; i < 2; ++i) {
    const int p = i * 256 + t;
    const int lr = p >> 5, j = p & 31;
    unq[(size_t)j * R + r0 + lr] = src[(size_t)(r0 + lr) * K + idxg[j]];
  }
}

// ---- kernel D: i8 GEMM (round-5 verbatim: 3-buf ring, 2-deep prefetch,
//      counted vmcnt(6), peeled tail, setprio) -- measured 178 us / 37%.
//      FROZEN: 7 structure variants (r4-r12) all land 177-228; this is the min.
__device__ __forceinline__ void gld_lds16(const signed char* g, signed char* l) {
  __builtin_amdgcn_global_load_lds(
      (const __attribute__((address_space(1))) void*)g,
      (__attribute__((address_space(3))) void*)l, 16, 0, 0);
}

__global__ __launch_bounds__(256, 2) void gemm_kernel(
    const signed char* __restrict__ xq, const signed char* __restrict__ wq,
    const _Float16* __restrict__ xmax, const _Float16* __restrict__ wmax,
    const float* __restrict__ xuf,   // [ALPHA][M]
    const float* __restrict__ wuf,   // [ALPHA][N]
    const float* __restrict__ bias,  // [N]
    float* __restrict__ out, int M, int N, int K) {
  __shared__ union {
    struct { signed char A[3][BM * BK]; signed char B[3][BN * BK]; } g;  // 72 KB, 3-buf
    struct { float xu[ALPHA * BM]; float wu[ALPHA * BN]; } e;            // 48 KB
  } sm;
  __shared__ _Float16 xmh[BM];
  __shared__ _Float16 wmh[BN];
  __shared__ float    bl[BN];

  const int t = threadIdx.x;
  // XCD-aware swizzle: 1024 blocks, 8 XCDs -> each XCD owns 4 consecutive bx.
  const int bid = blockIdx.y * gridDim.x + blockIdx.x;
  const int xcd = bid & 7, loc = bid >> 3;
  const int bxi = xcd * 4 + (loc & 3);
  const int byi = loc >> 2;
  const int bm0 = byi * BM;
  const int bn0 = bxi * BN;
  const int lane = t & 63, w = t >> 6;
  const int wm = w >> 1, wn = w & 1;       // 2x2 waves, wave tile 128x64
  const int hi = lane >> 5, l31 = lane & 31;

  i32x16 acc[4][2] = {};

  const int tp = t >> 7;                  // panel parity within an issue
  const int to = (t & 127) * 16;
  const signed char* aS = xq + (size_t)bm0 * K + (size_t)tp * 32 * K + to;
  const signed char* bS = wq + (size_t)bn0 * K + (size_t)tp * 32 * K + to;
  signed char* const aD = &sm.g.A[0][0] + t * 16;
  signed char* const bD = &sm.g.B[0][0] + t * 16;
  const size_t PSTR = (size_t)64 * K;     // 2-panel stride

  auto STAGE = [&](int buf, int kt) {
    const size_t ko = (size_t)kt * 2048;  // (kt*64)>>4 * 512
#pragma unroll
    for (int i = 0; i < 4; ++i)
      gld_lds16(aS + (size_t)i * PSTR + ko, aD + buf * (BM * BK) + i * 4096);
#pragma unroll
    for (int i = 0; i < 2; ++i)
      gld_lds16(bS + (size_t)i * PSTR + ko, bD + buf * (BN * BK) + i * 4096);
  };

  const int NT = K >> 6;   // 64
  STAGE(0, 0);
  STAGE(1, 1);
  const signed char* const aR0 = &sm.g.A[0][0] + (wm * 4) * 2048 + 16 * lane;
  const signed char* const bR0 = &sm.g.B[0][0] + (wn * 2) * 2048 + 16 * lane;

  int cur = 0, st = 2;
  for (int kt = 0; kt < NT - 1; ++kt) {
    // tile kt's loads were issued 2 iters ago: counted wait, never drain to 0.
    asm volatile("s_waitcnt vmcnt(6)" ::: "memory");
    asm volatile("s_barrier" ::: "memory");
    const signed char* aRd = aR0 + cur * (BM * BK);
    const signed char* bRd = bR0 + cur * (BN * BK);
    i32x4 af[2][4], bf[2][2];
#pragma unroll
    for (int ks = 0; ks < 2; ++ks) {
#pragma unroll
      for (int mi = 0; mi < 4; ++mi) af[ks][mi] = *(const i32x4*)(aRd + mi * 2048 + ks * 1024);
#pragma unroll
      for (int ni = 0; ni < 2; ++ni) bf[ks][ni] = *(const i32x4*)(bRd + ni * 2048 + ks * 1024);
    }
    if (kt + 2 < NT) STAGE(st, kt + 2);   // 2-deep prefetch
    __builtin_amdgcn_s_setprio(1);
#pragma unroll
    for (int ks = 0; ks < 2; ++ks)
#pragma unroll
      for (int mi = 0; mi < 4; ++mi)
#pragma unroll
        for (int ni = 0; ni < 2; ++ni)
          acc[mi][ni] = __builtin_amdgcn_mfma_i32_32x32x32_i8(af[ks][mi], bf[ks][ni], acc[mi][ni], 0, 0, 0);
    __builtin_amdgcn_s_setprio(0);
    if (++cur == 3) cur = 0;
    if (++st == 3) st = 0;
  }
  { // peeled last tile: only here do we drain
    asm volatile("s_waitcnt vmcnt(0)" ::: "memory");
    asm volatile("s_barrier" ::: "memory");
    const signed char* aRd = aR0 + cur * (BM * BK);
    const signed char* bRd = bR0 + cur * (BN * BK);
    i32x4 af[2][4], bf[2][2];
#pragma unroll
    for (int ks = 0; ks < 2; ++ks) {
#pragma unroll
      for (int mi = 0; mi < 4; ++mi) af[ks][mi] = *(const i32x4*)(aRd + mi * 2048 + ks * 1024);
#pragma unroll
      for (int ni = 0; ni < 2; ++ni) bf[ks][ni] = *(const i32x4*)(bRd + ni * 2048 + ks * 1024);
    }
    __builtin_amdgcn_s_setprio(1);
#pragma unroll
    for (int ks = 0; ks < 2; ++ks)
#pragma unroll
      for (int mi = 0; mi < 4; ++mi)
#pragma unroll
        for (int ni = 0; ni < 2; ++ni)
          acc[mi][ni] = __builtin_amdgcn_mfma_i32_32x32x32_i8(af[ks][mi], bf[ks][ni], acc[mi][ni], 0, 0, 0);
    __builtin_amdgcn_s_setprio(0);
  }

  __syncthreads();
  // ---- epilogue staging (reuses GEMM LDS) ----
  {
    const float4* xs = (const float4*)xuf;
    float4* xl = (float4*)sm.e.xu;
#pragma unroll
    for (int i = 0; i < 8; ++i) {   // 2048 float4
      int p = i * 256 + t;
      int j = p >> 6, r4 = p & 63;
      xl[p] = xs[(size_t)j * (M >> 2) + (bm0 >> 2) + r4];
    }
    const float4* wsrc = (const float4*)wuf;
    float4* wl = (float4*)sm.e.wu;
#pragma unroll
    for (int i = 0; i < 4; ++i) {   // 1024 float4
      int p = i * 256 + t;
      int j = p >> 5, r4 = p & 31;
      wl[p] = wsrc[(size_t)j * (N >> 2) + (bn0 >> 2) + r4];
    }
    if (t < BM / 2) ((unsigned*)xmh)[t] = ((const unsigned*)(xmax + bm0))[t];
    if (t < BN / 2) ((unsigned*)wmh)[t] = ((const unsigned*)(wmax + bn0))[t];
    if (t < BN / 4) ((float4*)bl)[t] = ((const float4*)(bias + bn0))[t];
  }
  __syncthreads();

  const int c0 = wn * 64 + l31;   // column (within tile) for ni=0; ni=1 is +32
  const _Float16 wh0 = wmh[c0], wh1 = wmh[c0 + 32];
  const float bv0 = bl[c0], bv1 = bl[c0 + 32];
  const float* xul = sm.e.xu;     // [ALPHA][BM]
  const float* wul = sm.e.wu;     // [ALPHA][BN]

#pragma unroll
  for (int mi = 0; mi < 4; ++mi) {
    const int rbase = wm * 128 + mi * 32 + 4 * hi;   // + (r&3) + 8*(r>>2)
    float f0[16], f1[16];
#pragma unroll
    for (int r = 0; r < 16; ++r) {
      int row = rbase + (r & 3) + 8 * (r >> 2);
      _Float16 xh = xmh[row];
      float mx0 = (float)(_Float16)(xh * wh0);   // fp16 multiply (subnormal-correct) like ref
      float mx1 = (float)(_Float16)(xh * wh1);
      f0[r] = (float)acc[mi][0][r] * mx0 + bv0;
      f1[r] = (float)acc[mi][1][r] * mx1 + bv1;
    }
#pragma unroll 4
    for (int j = 0; j < ALPHA; ++j) {            // rank-32 fp32 outlier update
      const float4* xrow4 = (const float4*)(xul + j * BM + rbase);
      float wv0 = wul[j * BN + c0];
      float wv1 = wul[j * BN + c0 + 32];
#pragma unroll
      for (int gq = 0; gq < 4; ++gq) {
        float4 xv = xrow4[gq * 2];               // rows rbase + 8*gq .. +3
        f0[gq * 4 + 0] += xv.x * wv0;  f1[gq * 4 + 0] += xv.x * wv1;
        f0[gq * 4 + 1] += xv.y * wv0;  f1[gq * 4 + 1] += xv.y * wv1;
        f0[gq * 4 + 2] += xv.z * wv0;  f1[gq * 4 + 2] += xv.z * wv1;
        f0[gq * 4 + 3] += xv.w * wv0;  f1[gq * 4 + 3] += xv.w * wv1;
      }
    }
#pragma unroll
    for (int r = 0; r < 16; ++r) {
      int row = bm0 + rbase + (r & 3) + 8 * (r >> 2);
      size_t o = (size_t)row * N + bn0;
      out[o + c0] = f0[r];
      out[o + c0 + 32] = f1[r];
    }
  }
}

// ---------------- launch ----------------
extern "C" void kernel_launch(void* const* d_in, const int* in_sizes, int n_in,
                              void* d_out, int out_size, void* d_ws, size_t ws_size,
                              hipStream_t stream) {
  const float* x       = (const float*)d_in[0];
  const float* W       = (const float*)d_in[1];
  const float* bias    = (const float*)d_in[2];
  const float* act_max = (const float*)d_in[3];
  const int K = in_sizes[3];            // 4096
  const int N = in_sizes[1] / K;        // 4096
  const int M = in_sizes[0] / K;        // 8192
  float* out = (float*)d_out;

  char* ws = (char*)d_ws;
  size_t off = 0;
  auto take = [&](size_t b) { char* p = ws + off; off += (b + 255) & ~(size_t)255; return p; };
  signed char* wq  = (signed char*)take((size_t)N * K);
  signed char* xq  = (signed char*)take((size_t)M * K);
  _Float16* wmax   = (_Float16*)take((size_t)N * 2);
  _Float16* xmax   = (_Float16*)take((size_t)M * 2);
  float* wuf       = (float*)take((size_t)ALPHA * N * 4);
  float* xuf       = (float*)take((size_t)ALPHA * M * 4);
  int* idx         = (int*)take(ALPHA * 4);
  unsigned* tbits  = (unsigned*)take((size_t)(K / 32) * 4);

  topk_kernel<<<1, 256, 0, stream>>>(act_max, idx, tbits, K);
  quant16_kernel<<<(N + M) / 16, 256, 0, stream>>>(W, x, tbits, idx, wq, xq,
                                                   wmax, xmax, wuf, xuf, K, N, M);
  dim3 grid(N / BN, M / BM);
  gemm_kernel<<<grid, 256, 0, stream>>>(xq, wq, xmax, wmax, xuf, wuf, bias, out, M, N, K);
}